// Round 12
// baseline (88.174 us; speedup 1.0000x reference)
//
#include <hip/hip_runtime.h>
#include <math.h>

#define NTOK 16384
#define DDIM 2048
#define NEXP 64
#define MT   64                  // tokens per block (= lanes of a wave)
#define KSPLIT 8
#define KRANGE (DDIM / KSPLIT)   // 256
#define KC   32                  // k per LDS chunk
#define NCH  (KRANGE / KC)       // 8

// ws layout (floats): [0..63] f counts, [64..127] P sums, [128] sum lse^2,
// [PART_OFF ...] partial logits [KSPLIT][NTOK][NEXP],
// [WT_OFF ...] transposed W [4 groups][DDIM][16]
#define PART_OFF 256
#define WT_OFF   (PART_OFF + KSPLIT * NTOK * NEXP)

// Flat-GEMM: wave = 64 tokens (lane = token) x 16 experts. W rows are
// wave-uniform -> s_load_dwordx16 (scalar pipe: zero VALU/LDS cost); x in
// LDS, 1 ds_read_b128 per 64 FMA-inst -> LDS pipe ~30k cyc/CU << 65.5k FMA
// wall. E=16 doubles the FMA run between lgkmcnt wait-points vs E=8 (r11).
// 8 blocks/CU = 8 independent barrier groups hide each other's stalls.

__device__ __forceinline__ void gload16(const float* g, const float* lds) {
    __builtin_amdgcn_global_load_lds(
        (const __attribute__((address_space(1))) unsigned int*)g,
        (__attribute__((address_space(3))) unsigned int*)lds, 16, 0, 0);
}

// prep: zero the accumulators and build wt[g][k][j] = W[k][g*16+j]
__global__ __launch_bounds__(256) void prep_wt(
    const float* __restrict__ W, float* __restrict__ ws)
{
    const int i = blockIdx.x * 256 + threadIdx.x;   // 0 .. 131071
    if (blockIdx.x == 0 && threadIdx.x < 129) ws[threadIdx.x] = 0.0f;
    const int k = i >> 6, e = i & 63;
    ws[WT_OFF + (size_t)(e >> 4) * (DDIM * 16) + k * 16 + (e & 15)] = W[i];
}

__global__ __launch_bounds__(256, 8) void gemm_part(
    const float* __restrict__ x, const float* __restrict__ wt,
    float* __restrict__ pws)
{
    __shared__ __align__(16) float xb[2][MT * KC];   // 2 x 8 KB

    const int tid  = threadIdx.x;
    const int tb   = blockIdx.x & (NTOK / MT - 1);  // token block 0..255
    const int s    = blockIdx.x >> 8;               // k-split 0..7
    const int tok0 = tb * MT;
    const int kb   = s * KRANGE;

    const int lane = tid & 63;                       // token within block
    const int g    = __builtin_amdgcn_readfirstlane(tid >> 6); // expert group

    // staging: 2 x 16 B per thread; slot o = u*1024 + tid*4 floats ->
    // row = u*32 + (tid>>3), lds granule = tid&7;
    // global granule = (tid&7) ^ (row&7) = (tid&7) ^ ((tid>>3)&7)  (u-inv.)
    const int srow = tid >> 3;                       // + u*32
    const int sg   = (tid & 7) ^ (srow & 7);
    const float* xsrc0 = x + (size_t)(tok0 + srow) * DDIM + kb + (sg << 2);
    const float* xsrc1 = xsrc0 + (size_t)32 * DDIM;

    float acc[16];
    #pragma unroll
    for (int j = 0; j < 16; ++j) acc[j] = 0.0f;

    const int l7    = lane & 7;
    const int xbase = lane * KC;                     // lane's row (floats)
    const float* wks = wt + (size_t)g * (DDIM * 16) + (size_t)kb * 16;

    gload16(xsrc0, &xb[0][tid * 4]);
    gload16(xsrc1, &xb[0][1024 + tid * 4]);

    #pragma unroll 1
    for (int cc = 0; cc < NCH; cc += 2) {
        #pragma unroll
        for (int h = 0; h < 2; ++h) {
            const int c = cc + h;                    // c&1 == h
            __syncthreads();   // chunk c staged (vmcnt drained); buf h free
            if (c + 1 < NCH) {
                gload16(xsrc0 + (c + 1) * KC, &xb[h ^ 1][tid * 4]);
                gload16(xsrc1 + (c + 1) * KC, &xb[h ^ 1][1024 + tid * 4]);
            }
            const float* xcb = xb[h];
            const float* wkc = wks + (size_t)c * KC * 16;  // contiguous chunk
            #pragma unroll
            for (int s2 = 0; s2 < KC / 4; ++s2) {
                float xv[4];
                *(float4*)xv =
                    *(const float4*)&xcb[xbase + ((s2 ^ l7) << 2)];
                #pragma unroll
                for (int r = 0; r < 4; ++r) {        // k ascending
                    const float* wrow = wkc + (size_t)(4 * s2 + r) * 16;
                    #pragma unroll
                    for (int j = 0; j < 16; ++j)     // wrow[j]: SGPR operand
                        acc[j] = fmaf(xv[r], wrow[j], acc[j]);
                }
            }
        }
    }

    // store partial logits pws[s][tok][e]
    float* pb = pws + ((size_t)s * NTOK + tok0) * NEXP + (size_t)lane * NEXP
              + g * 16;
    #pragma unroll
    for (int q = 0; q < 4; ++q)
        *(float4*)&pb[q * 4] = *(float4*)&acc[q * 4];
}

#define ETOK 64   // tokens per epilogue block

__global__ __launch_bounds__(256) void epilogue(
    const float* __restrict__ pws, const float* __restrict__ bias,
    float* __restrict__ out, float* __restrict__ acc_g)
{
    __shared__ int   f_loc[NEXP];
    __shared__ float p_loc[NEXP];
    __shared__ float z_loc;

    const int tid = threadIdx.x;
    const int tx  = tid & 15;         // expert group: 4tx..4tx+3
    const int tg  = tid >> 4;         // token slot 0..15
    const int e0  = tx * 4;

    if (tid < NEXP) { f_loc[tid] = 0; p_loc[tid] = 0.0f; }
    if (tid == 0) z_loc = 0.0f;
    __syncthreads();

    float bb[4];
    *(float4*)bb = *(const float4*)&bias[e0];

    float pacc[4] = {0.f, 0.f, 0.f, 0.f};
    float zacc = 0.0f;

    for (int it = 0; it < ETOK / 16; ++it) {
        const int gt = blockIdx.x * ETOK + it * 16 + tg;

        // sum 8 partials in fixed ascending-s order, then + bias
        float l[4];
        {
            const size_t ro = (size_t)gt * NEXP + e0;
            float4 q[KSPLIT];
            #pragma unroll
            for (int sp = 0; sp < KSPLIT; ++sp)
                q[sp] = *(const float4*)&pws[(size_t)sp * NTOK * NEXP + ro];
            float a0 = q[0].x, a1 = q[0].y, a2 = q[0].z, a3 = q[0].w;
            #pragma unroll
            for (int sp = 1; sp < KSPLIT; ++sp) {
                a0 += q[sp].x; a1 += q[sp].y; a2 += q[sp].z; a3 += q[sp].w;
            }
            l[0] = a0 + bb[0]; l[1] = a1 + bb[1];
            l[2] = a2 + bb[2]; l[3] = a3 + bb[3];
        }

        // local top-2 (stable: ascending e, strict >)
        float v1 = l[0], v2 = -INFINITY;
        int   i1 = e0,   i2 = 0x7fffffff;
        #pragma unroll
        for (int j = 1; j < 4; ++j) {
            float v = l[j]; int e = e0 + j;
            if (v > v1)      { v2 = v1; i2 = i1; v1 = v; i1 = e; }
            else if (v > v2) { v2 = v;  i2 = e; }
        }
        // merge across the 16 lanes of this token (value desc, idx asc)
        #pragma unroll
        for (int off = 1; off < 16; off <<= 1) {
            float o1 = __shfl_xor(v1, off, 16); int oi1 = __shfl_xor(i1, off, 16);
            float o2 = __shfl_xor(v2, off, 16); int oi2 = __shfl_xor(i2, off, 16);
            if (o1 > v1 || (o1 == v1 && oi1 < i1)) {
                float cs = v1; int ci = i1;
                v1 = o1; i1 = oi1;
                if (cs > o2 || (cs == o2 && ci < oi2)) { v2 = cs; i2 = ci;  }
                else                                   { v2 = o2; i2 = oi2; }
            } else {
                if (o1 > v2 || (o1 == v2 && oi1 < i2)) { v2 = o1; i2 = oi1; }
            }
        }
        const float mx = v1;

        float sden[4], dsum = 0.0f;
        #pragma unroll
        for (int j = 0; j < 4; ++j) { sden[j] = __expf(l[j] - mx); dsum += sden[j]; }
        #pragma unroll
        for (int off = 1; off < 16; off <<= 1) dsum += __shfl_xor(dsum, off, 16);
        const float inv = 1.0f / dsum;

        float zsum = 0.0f;
        #pragma unroll
        for (int j = 0; j < 4; ++j) {
            float pj = sden[j] * inv;
            pacc[j] += pj;
            zsum += __expf(pj);
        }
        #pragma unroll
        for (int off = 1; off < 16; off <<= 1) zsum += __shfl_xor(zsum, off, 16);

        if (tx == 0) {
            const float s2 = __expf(v2 - mx);      // s1 == 1
            const float ci = 1.0f / (1.0f + s2);
            out[2 * gt]     = (float)i1;
            out[2 * gt + 1] = (float)i2;
            out[2 * NTOK + 2 * gt]     = ci;
            out[2 * NTOK + 2 * gt + 1] = s2 * ci;
            atomicAdd(&f_loc[i1], 1);
            float lse = __logf(zsum);
            zacc += lse * lse;
        }
    }

    // z: wave-reduce (only tx==0 lanes carry nonzero), one LDS atomic per wave
    #pragma unroll
    for (int off = 1; off < 64; off <<= 1) zacc += __shfl_xor(zacc, off);
    if ((tid & 63) == 0) atomicAdd(&z_loc, zacc);

    // P: fold token-groups within wave, then LDS
    #pragma unroll
    for (int j = 0; j < 4; ++j) {
        pacc[j] += __shfl_xor(pacc[j], 16);
        pacc[j] += __shfl_xor(pacc[j], 32);
    }
    if ((tid & 63) < 16) {
        #pragma unroll
        for (int j = 0; j < 4; ++j) atomicAdd(&p_loc[e0 + j], pacc[j]);
    }

    __syncthreads();
    if (tid < NEXP) {
        atomicAdd(&acc_g[64 + tid], p_loc[tid]);
        if (f_loc[tid]) atomicAdd(&acc_g[tid], (float)f_loc[tid]);
    }
    if (tid == 0) atomicAdd(&acc_g[128], z_loc);
}

__global__ void gate_finalize(const float* __restrict__ acc, float* __restrict__ out) {
    int e = threadIdx.x;  // 64 threads
    float v = acc[e] * acc[64 + e];
    #pragma unroll
    for (int off = 32; off > 0; off >>= 1) v += __shfl_down(v, off);
    if (e == 0) {
        const float NT = (float)NTOK;
        out[2 * NTOK * 2]     = 0.01f * (v / (float)NEXP) / (NT * NT);
        out[2 * NTOK * 2 + 1] = 0.1f * acc[128] / NT;
    }
}

extern "C" void kernel_launch(void* const* d_in, const int* in_sizes, int n_in,
                              void* d_out, int out_size, void* d_ws, size_t ws_size,
                              hipStream_t stream) {
    const float* x    = (const float*)d_in[0];
    const float* W    = (const float*)d_in[1];
    const float* bias = (const float*)d_in[2];
    float* out = (float*)d_out;
    float* ws  = (float*)d_ws;
    float* pws = ws + PART_OFF;
    float* wts = ws + WT_OFF;

    prep_wt<<<(DDIM * NEXP) / 256, 256, 0, stream>>>(W, ws);
    gemm_part<<<KSPLIT * (NTOK / MT), 256, 0, stream>>>(x, wts, pws);
    epilogue<<<NTOK / ETOK, 256, 0, stream>>>(pws, bias, out, ws);
    gate_finalize<<<1, 64, 0, stream>>>(ws, out);
}